// Round 7
// baseline (200.706 us; speedup 1.0000x reference)
//
#include <hip/hip_runtime.h>

#define DDIM 256
#define NTOK 4096   // B*S = 64*64
#define NEGN 8192
#define LOG2E 1.4426950408889634f
// small 64x64 kernel (fr alignment)
#define TM 64
#define TN 64
#define LDT 40      // padded halfs per LDS row for the small kernel

typedef __attribute__((ext_vector_type(8))) short bf16x8;
typedef __attribute__((ext_vector_type(4))) float f32x4;

__device__ inline unsigned short f2bf(float f) {
    unsigned int u = __float_as_uint(f);
    unsigned int r = u + 0x7FFFu + ((u >> 16) & 1u);
    return (unsigned short)(r >> 16);
}

// bare v_exp_f32: computes 2^x (inputs are pre-scaled by log2(e) at gather)
__device__ inline float exp2fast(float x) {
    float r;
    asm("v_exp_f32 %0, %1" : "=v"(r) : "v"(x));
    return r;
}

// global->LDS direct DMA, 16B/lane; LDS dest = wave-uniform base + lane*16.
__device__ inline void gl_lds16(const unsigned short* g, unsigned short* l) {
    __builtin_amdgcn_global_load_lds(
        reinterpret_cast<__attribute__((address_space(1))) unsigned int*>(
            reinterpret_cast<uintptr_t>(g)),
        reinterpret_cast<__attribute__((address_space(3))) unsigned int*>(
            reinterpret_cast<uintptr_t>(l)),
        16, 0, 0);
}

__device__ inline void wait_vmcnt0() { asm volatile("s_waitcnt vmcnt(0)" ::: "memory"); }
__device__ inline void raw_barrier() { asm volatile("s_barrier" ::: "memory"); }

// DPP 16-lane sum reduction — VALU only.
template<int CTRL>
__device__ inline float dpp_add(float x) {
    int v = __builtin_amdgcn_update_dpp(0, __float_as_int(x), CTRL, 0xF, 0xF, false);
    return x + __int_as_float(v);
}
__device__ inline float red16(float x) {
    x = dpp_add<0xB1>(x);    // quad_perm [1,0,3,2]
    x = dpp_add<0x4E>(x);    // quad_perm [2,3,0,1]
    x = dpp_add<0x141>(x);   // row_half_mirror
    x = dpp_add<0x140>(x);   // row_mirror
    return x;
}

// ---------------------------------------------------------------------------
// Kernel 1: gather + fp32->bf16 convert + fused en_score + denom zero-init.
// E rows are pre-scaled by log2(e) so kernel 2's exp is a bare v_exp_f32.
// z_bf is NOT scaled (kernel 3 consumes it as the B operand).
// (unchanged from R4/R5/R6)
// ---------------------------------------------------------------------------
__global__ void gather_kernel(
    const float* __restrict__ zs,
    const float* __restrict__ W_en, const float* __restrict__ W_fr,
    const int* __restrict__ pos_en, const int* __restrict__ neg_en,
    const int* __restrict__ pos_fr, const int* __restrict__ neg_fr,
    const int* __restrict__ x_en,
    unsigned short* __restrict__ z_bf,
    unsigned short* __restrict__ E_en, unsigned short* __restrict__ E_fr,
    float* __restrict__ en_score,
    float* __restrict__ denom_en, float* __restrict__ denom_fr,
    int Pe, int Pf, int Lpe, int Lpf)
{
    int row  = blockIdx.x * 4 + (threadIdx.x >> 6);
    int lane = threadIdx.x & 63;
    const float* src = nullptr;
    unsigned short* dst = nullptr;
    bool zero = false;
    float sc = LOG2E;                 // E rows get the log2e pre-scale

    if (row < NTOK) {
        src = zs + (size_t)row * DDIM;
        dst = z_bf + (size_t)row * DDIM;
        sc = 1.0f;                    // z_bf stays unscaled
        if (lane == 0) { denom_en[row] = 0.0f; denom_fr[row] = 0.0f; }
    } else if (row < NTOK + Lpe) {
        int j = row - NTOK;
        int Le = Pe + NEGN;
        int idx = 0;
        if (j < Pe)      idx = pos_en[j];
        else if (j < Le) idx = neg_en[j - Pe];
        else             zero = true;
        src = W_en + (size_t)idx * DDIM;
        dst = E_en + (size_t)j * DDIM;
    } else if (row < NTOK + Lpe + Lpf) {
        int j = row - NTOK - Lpe;
        int Lf = Pf + NEGN;
        int idx = 0;
        if (j < Pf)      idx = pos_fr[j];
        else if (j < Lf) idx = neg_fr[j - Pf];
        else             zero = true;
        src = W_fr + (size_t)idx * DDIM;
        dst = E_fr + (size_t)j * DDIM;
    } else if (row < NTOK + Lpe + Lpf + NTOK) {
        // fused en_score: zs[j] . W_en[x_en[j]] in fp32, wave reduce
        int j = row - NTOK - Lpe - Lpf;
        int idx = x_en[j];
        float4 z = *(const float4*)(zs   + (size_t)j   * DDIM + lane * 4);
        float4 w = *(const float4*)(W_en + (size_t)idx * DDIM + lane * 4);
        float s = z.x * w.x + z.y * w.y + z.z * w.z + z.w * w.w;
        #pragma unroll
        for (int m = 32; m; m >>= 1) s += __shfl_xor(s, m);
        if (lane == 0) en_score[j] = s;
        return;
    } else {
        return;
    }

    int d = lane * 4;
    float4 v;
    if (zero) { v.x = v.y = v.z = v.w = 0.0f; }
    else      { v = *(const float4*)(src + d); }
    ushort4 o;
    o.x = f2bf(v.x * sc); o.y = f2bf(v.y * sc);
    o.z = f2bf(v.z * sc); o.w = f2bf(v.w * sc);
    *(ushort4*)(dst + d) = o;
}

// ---------------------------------------------------------------------------
// Kernel 2: fused denominators — 4 DOMAINS x 4 WAVES/SIMD (+ T5 setprio).
// Evidence matrix R2..R6: MFMA-busy TIME is invariant (~20.6us) across all
// structures; pipes sum instead of overlap. R5: 4 w/SIMD, 1 domain -> 65us.
// R6: 3 domains, 3 w/SIMD -> 62us. The untested quadrant: 4 w/SIMD each
// from a DIFFERENT unsynced block. This is R6 with launch_bounds(256,4),
// grid 1024 (32 m-granules x 32 XCD-aligned slices = exactly 4 blocks/CU;
// LDS 4 x 32KB = 128 <= 160KB; per-wave regs ~110 incl acc <= 128 bin ->
// 4 waves/SIMD granted). Each SIMD then holds one wave from each of 4
// independent pipelines; s_setprio(1) around the MFMA sweeps (T5) makes the
// scheduler prefer whichever wave is in its MFMA phase — the cross-wave
// overlap all previous rounds failed to force (null on lockstep per m190,
// +21-39% with role diversity per m218b).
// Tile = 32n x 256k (16 KB) double-buffered; staging/layout/sync verbatim
// R6 (HW-verified absmax 0.0): wave w stages sub-block (w&1), chunks
// [4*(w>>1),+4), 4 x 1KB lane-linear DMAs; own vmcnt(0) -> raw s_barrier.
// Frag layouts (HW-verified): A/B lane holds row (lane&15), 8 k-halfs at
// (lane>>4)*8;  C/D: n-col = lane&15, m-row = (lane>>4)*4 + reg.
// ---------------------------------------------------------------------------
__global__ __launch_bounds__(256, 4) void expsum_stream(
    const unsigned short* __restrict__ A,   // z_bf [4096 x 256]
    const unsigned short* __restrict__ E,   // [Ltot x 256], pre-scaled log2e
    const float* __restrict__ kep, const float* __restrict__ kfp,
    float* __restrict__ out_en, float* __restrict__ out_fr,
    int Pe, int Pf, int Lpe, int NT)        // NT = Ltot/32 n-tiles (32-row)
{
    // 2 buffers x (8 chunks x 2 sub-blocks x 512 halfs) = 2 x 16 KB.
    // Sub-block = 16 rows x 32 k-halfs, lane-linear (lane*16B): DMA write
    // and b128 fragment read share the proven zero-conflict pattern.
    __shared__ __align__(16) unsigned short Bs[2][8192];

    // 1024 blocks: xcd = lin&7, slice sl = xcd + 8*((lin>>3)&3) in [0,32),
    // m-granule mg = lin>>5 in [0,32) (128 rows; wave owns 32).
    // XCD k streams only tiles ≡ k (mod 8) -> its 1/8 of E L2-resident.
    int lin = blockIdx.y * 64 + blockIdx.x;
    int xcd = lin & 7;
    int sl  = xcd + 8 * ((lin >> 3) & 3);  // 0..31
    int mg  = lin >> 5;                    // 0..31

    int t    = threadIdx.x;
    int lane = t & 63;
    int wave = t >> 6;                 // 0..3
    int col  = lane & 15;
    int quad = lane >> 4;

    // kappas: load + pin BEFORE any DMA so the vmcnt queue stays clean
    float ke = kep[0], kf = kfp[0];
    asm volatile("" : "+v"(ke), "+v"(kf) : : "memory");

    // ---- A fragments in registers (one-time load; wave owns 32 m rows)
    bf16x8 afr[2][8];
    {
        const unsigned short* Ap =
            A + ((size_t)(mg * 128 + wave * 32 + col)) * DDIM + quad * 8;
        #pragma unroll
        for (int i = 0; i < 2; i++)
            #pragma unroll
            for (int c = 0; c < 8; c++)
                afr[i][c] = *(const bf16x8*)(Ap + (size_t)i * 16 * DDIM + c * 32);
    }

    float sums[2][4];
    #pragma unroll
    for (int i = 0; i < 2; i++)
        #pragma unroll
        for (int rr = 0; rr < 4; rr++) sums[i][rr] = 0.0f;

    f32x4 accA[2], accB[2];
    #pragma unroll
    for (int i = 0; i < 2; i++) accB[i] = (f32x4){0.f, 0.f, 0.f, 0.f};
    float wjP = 0.0f;                  // weight of the pending (accB) n-frag
    float* curout = out_en;
    int outrow = mg * 128 + wave * 32;

    int ntiles = (NT - sl + 31) >> 5;

    // stage tile s: wave w stages sub-block (w&1) of chunks [4*(w>>1),+4):
    // 4 DMAs of 1 KB (16 rows x 32 k-halfs each, lane-linear dest).
    #define STAGE_TILE(s) do {                                               \
        int tl_ = sl + ((s) << 5);                                           \
        int sub_ = wave & 1;                                                 \
        int c0_  = (wave >> 1) * 4;                                          \
        const unsigned short* g_ =                                           \
            E + (size_t)(tl_ * 32 + sub_ * 16 + col) * DDIM + quad * 8;      \
        unsigned short* l_ = &Bs[(s) & 1][sub_ * 512];                       \
        _Pragma("unroll")                                                    \
        for (int d_ = 0; d_ < 4; d_++)                                       \
            gl_lds16(g_ + (c0_ + d_) * 32, l_ + (c0_ + d_) * 1024);          \
    } while (0)

    // full-K sweep for n-frag J: compute ACCC (2 MFMAs/chunk); drain ACCD
    // (weight WJD) under the MFMAs, 1 entry per chunk (8 over 8 chunks).
    // setprio(1) over the sweep: with 4 independent blocks per SIMD, the CU
    // scheduler favors the wave in its MFMA phase (T5, role-diversity case).
    #define J_SWEEP(J, ACCC, ACCD, WJD) do {                                 \
        _Pragma("unroll")                                                    \
        for (int i = 0; i < 2; i++) ACCC[i] = (f32x4){0.f, 0.f, 0.f, 0.f};   \
        __builtin_amdgcn_s_setprio(1);                                       \
        _Pragma("unroll")                                                    \
        for (int k8 = 0; k8 < 8; k8++) {                                     \
            bf16x8 bfv = *(const bf16x8*)(                                   \
                &Bs[s & 1][k8 * 1024 + (J) * 512 + quad * 128 + col * 8]);   \
            ACCC[0] = __builtin_amdgcn_mfma_f32_16x16x32_bf16(               \
                afr[0][k8], bfv, ACCC[0], 0, 0, 0);                          \
            ACCC[1] = __builtin_amdgcn_mfma_f32_16x16x32_bf16(               \
                afr[1][k8], bfv, ACCC[1], 0, 0, 0);                          \
            sums[k8 >> 2][k8 & 3] +=                                         \
                (WJD) * exp2fast(ACCD[k8 >> 2][k8 & 3]);                     \
        }                                                                    \
        __builtin_amdgcn_s_setprio(0);                                       \
    } while (0)

    #define FLUSH_SUMS() do {                                                \
        _Pragma("unroll")                                                    \
        for (int i = 0; i < 2; i++)                                          \
            _Pragma("unroll")                                                \
            for (int rr = 0; rr < 4; rr++) {                                 \
                float v = red16(sums[i][rr]);                                \
                if (col == 0)                                                \
                    atomicAdd(curout + outrow + 16 * i + quad * 4 + rr, v);  \
                sums[i][rr] = 0.0f;                                          \
            }                                                                \
    } while (0)

    STAGE_TILE(0);

    for (int s = 0; s < ntiles; s++) {
        int tl = sl + (s << 5);
        int nb = tl * 32;

        wait_vmcnt0();      // my tile-s DMAs retired (issued 1 tile-period ago)
        raw_barrier();      // all waves' tile-s resident; all done reading s-1

        if (s + 1 < ntiles) STAGE_TILE(s + 1);   // 4 DMAs, fly under compute

        // arithmetic weights: n < P -> 1 ; n < P+NEGN -> kappa ; else 0 (pad)
        float wj[2];
        #pragma unroll
        for (int j = 0; j < 2; j++) {
            int ngl = nb + 16 * j + col;
            if (nb < Lpe) {
                wj[j] = (ngl < Pe) ? 1.0f : ((ngl < Pe + NEGN) ? ke : 0.0f);
            } else {
                int nl = ngl - Lpe;
                wj[j] = (nl < Pf) ? 1.0f : ((nl < Pf + NEGN) ? kf : 0.0f);
            }
        }
        float* outC = (nb >= Lpe) ? out_fr : out_en;

        // j0: drains the pending frag (prev tile's j1, weight wjP, out curout)
        J_SWEEP(0, accA, accB, wjP);
        if (outC != curout) {          // en->fr boundary: taken once per block
            FLUSH_SUMS();
            curout = outC;
        }
        J_SWEEP(1, accB, accA, wj[0]);
        wjP = wj[1];                   // accB (j1) pends into the next tile
    }
    #undef STAGE_TILE
    #undef J_SWEEP

    // drain the final pending frag, then flush
    #pragma unroll
    for (int i = 0; i < 2; i++)
        #pragma unroll
        for (int rr = 0; rr < 4; rr++)
            sums[i][rr] += wjP * exp2fast(accB[i][rr]);
    FLUSH_SUMS();
    #undef FLUSH_SUMS
}

// ---------------------------------------------------------------------------
// Kernel 3: fr alignment (per-batch 64x64 exp-sum, weight 1/denom_fr) with
// inline W_fr[x_fr] gather+convert for A (pre-scaled by log2e -> bare
// v_exp_f32) and the final loss fused in. (unchanged from R4/R5/R6)
// ---------------------------------------------------------------------------
__global__ __launch_bounds__(256) void expsum_gemm64_loss(
    const float* __restrict__ W_fr,         // [V_FR x 256] fp32
    const int* __restrict__ x_fr,           // [B*64]
    const unsigned short* __restrict__ Bm,  // z_bf  [B][64 x 256]
    const float* __restrict__ denom_fr,     // [B*64]
    const float* __restrict__ denom_en,     // [B*64]
    const float* __restrict__ en_score,     // [B*64]
    const float* __restrict__ en_mask,
    const float* __restrict__ fr_mask,
    float* __restrict__ outloss)            // [128]: en | fr
{
    __shared__ __align__(16) unsigned short lda[TM * LDT];
    __shared__ __align__(16) unsigned short ldb[TN * LDT];
    __shared__ float tbuf[64];

    int batch = blockIdx.x;
    const unsigned short* Bb = Bm + (size_t)batch * TN * DDIM;

    int t      = threadIdx.x;
    int srow   = t >> 2;
    int schunk = t & 3;
    int lane   = t & 63;
    int wave   = t >> 6;
    int col    = lane & 15;
    int quad   = lane >> 4;

    int aidx = x_fr[batch * 64 + srow];
    const float* Arow = W_fr + (size_t)aidx * DDIM;

    f32x4 acc0 = {0.f,0.f,0.f,0.f};
    f32x4 acc1 = {0.f,0.f,0.f,0.f};
    f32x4 acc2 = {0.f,0.f,0.f,0.f};
    f32x4 acc3 = {0.f,0.f,0.f,0.f};

    for (int kk = 0; kk < DDIM; kk += 32) {
        float4 f0 = *(const float4*)(Arow + kk + schunk * 8);
        float4 f1 = *(const float4*)(Arow + kk + schunk * 8 + 4);
        uint4 bv = *(const uint4*)(Bb + (size_t)srow * DDIM + kk + schunk * 8);
        ushort4 ua; ua.x = f2bf(f0.x * LOG2E); ua.y = f2bf(f0.y * LOG2E);
                    ua.z = f2bf(f0.z * LOG2E); ua.w = f2bf(f0.w * LOG2E);
        ushort4 ub; ub.x = f2bf(f1.x * LOG2E); ub.y = f2bf(f1.y * LOG2E);
                    ub.z = f2bf(f1.z * LOG2E); ub.w = f2bf(f1.w * LOG2E);
        __syncthreads();
        *(ushort4*)(lda + srow * LDT + schunk * 8)     = ua;
        *(ushort4*)(lda + srow * LDT + schunk * 8 + 4) = ub;
        *(uint4*)(ldb + srow * LDT + schunk * 8) = bv;
        __syncthreads();

        bf16x8 af = *(const bf16x8*)(lda + (wave * 16 + col) * LDT + quad * 8);
        bf16x8 b0 = *(const bf16x8*)(ldb + ( 0 + col) * LDT + quad * 8);
        bf16x8 b1 = *(const bf16x8*)(ldb + (16 + col) * LDT + quad * 8);
        bf16x8 b2 = *(const bf16x8*)(ldb + (32 + col) * LDT + quad * 8);
        bf16x8 b3 = *(const bf16x8*)(ldb + (48 + col) * LDT + quad * 8);
        acc0 = __builtin_amdgcn_mfma_f32_16x16x32_bf16(af, b0, acc0, 0, 0, 0);
        acc1 = __builtin_amdgcn_mfma_f32_16x16x32_bf16(af, b1, acc1, 0, 0, 0);
        acc2 = __builtin_amdgcn_mfma_f32_16x16x32_bf16(af, b2, acc2, 0, 0, 0);
        acc3 = __builtin_amdgcn_mfma_f32_16x16x32_bf16(af, b3, acc3, 0, 0, 0);
    }

    const float* db = denom_fr + batch * 64;
    float w0 = 1.0f / db[ 0 + col];
    float w1 = 1.0f / db[16 + col];
    float w2 = 1.0f / db[32 + col];
    float w3 = 1.0f / db[48 + col];

    float tot0 = w0 * exp2fast(acc0.x) + w1 * exp2fast(acc1.x) + w2 * exp2fast(acc2.x) + w3 * exp2fast(acc3.x);
    float tot1 = w0 * exp2fast(acc0.y) + w1 * exp2fast(acc1.y) + w2 * exp2fast(acc2.y) + w3 * exp2fast(acc3.y);
    float tot2 = w0 * exp2fast(acc0.z) + w1 * exp2fast(acc1.z) + w2 * exp2fast(acc2.z) + w3 * exp2fast(acc3.z);
    float tot3 = w0 * exp2fast(acc0.w) + w1 * exp2fast(acc1.w) + w2 * exp2fast(acc2.w) + w3 * exp2fast(acc3.w);

    #pragma unroll
    for (int m = 1; m < 16; m <<= 1) {
        tot0 += __shfl_xor(tot0, m);
        tot1 += __shfl_xor(tot1, m);
        tot2 += __shfl_xor(tot2, m);
        tot3 += __shfl_xor(tot3, m);
    }
    if (col == 0) {
        int base = wave * 16 + quad * 4;
        tbuf[base + 0] = tot0; tbuf[base + 1] = tot1;
        tbuf[base + 2] = tot2; tbuf[base + 3] = tot3;
    }
    __syncthreads();

    if (t < 64) {
        int i = batch * 64 + t;
        float a = (en_score[i] - __logf(denom_en[i])) * en_mask[i];
        float c = __logf(tbuf[t]) * fr_mask[i];
        #pragma unroll
        for (int m = 32; m; m >>= 1) { a += __shfl_xor(a, m); c += __shfl_xor(c, m); }
        if (t == 0) { outloss[batch] = a; outloss[64 + batch] = c; }
    }
}

extern "C" void kernel_launch(void* const* d_in, const int* in_sizes, int n_in,
                              void* d_out, int out_size, void* d_ws, size_t ws_size,
                              hipStream_t stream)
{
    const float* zs       = (const float*)d_in[0];
    const int*   x_en     = (const int*)d_in[1];
    const int*   x_fr     = (const int*)d_in[2];
    const float* en_mask  = (const float*)d_in[3];
    const float* fr_mask  = (const float*)d_in[4];
    const float* W_en     = (const float*)d_in[5];
    const float* W_fr     = (const float*)d_in[6];
    const int*   pos_en   = (const int*)d_in[7];
    const int*   neg_en   = (const int*)d_in[8];
    const int*   pos_fr   = (const int*)d_in[9];
    const int*   neg_fr   = (const int*)d_in[10];
    const float* kappa_en = (const float*)d_in[11];
    const float* kappa_fr = (const float*)d_in[12];

    int Pe  = in_sizes[7];
    int Pf  = in_sizes[9];
    int Lpe = (Pe + NEGN + 63) & ~63;     // 64-aligned (32-tile no-straddle)
    int Lpf = (Pf + NEGN + 63) & ~63;
    int Ltot = Lpe + Lpf;
    int NT32 = Ltot / 32;                 // 32-row n-tiles

    char* w = (char*)d_ws;
    float* denom_en = (float*)w; w += NTOK * 4;
    float* denom_fr = (float*)w; w += NTOK * 4;
    float* en_score = (float*)w; w += NTOK * 4;
    unsigned short* z_bf  = (unsigned short*)w; w += (size_t)NTOK * DDIM * 2;
    unsigned short* E_all = (unsigned short*)w; w += (size_t)Ltot * DDIM * 2;

    int totrows = NTOK + Lpe + Lpf + NTOK;
    gather_kernel<<<(totrows + 3) / 4, 256, 0, stream>>>(
        zs, W_en, W_fr, pos_en, neg_en, pos_fr, neg_fr, x_en,
        z_bf, E_all, E_all + (size_t)Lpe * DDIM,
        en_score, denom_en, denom_fr, Pe, Pf, Lpe, Lpf);

    // fused denominators: 4 independent 4-wave pipelines per CU + setprio
    expsum_stream<<<dim3(64, 16), 256, 0, stream>>>(
        z_bf, E_all, kappa_en, kappa_fr, denom_en, denom_fr, Pe, Pf, Lpe, NT32);

    // fr alignment + inline W_fr gather (log2e-scaled) + fused loss
    expsum_gemm64_loss<<<64, 256, 0, stream>>>(
        W_fr, x_fr, z_bf, denom_fr, denom_en, en_score, en_mask, fr_mask,
        (float*)d_out);
}

// Round 8
// 190.351 us; speedup vs baseline: 1.0544x; 1.0544x over previous
//
#include <hip/hip_runtime.h>

#define DDIM 256
#define NTOK 4096   // B*S = 64*64
#define NEGN 8192
#define LOG2E 1.4426950408889634f
// small 64x64 kernel (fr alignment)
#define TM 64
#define TN 64
#define LDT 40      // padded halfs per LDS row for the small kernel

typedef __attribute__((ext_vector_type(8))) short bf16x8;
typedef __attribute__((ext_vector_type(4))) float f32x4;

__device__ inline unsigned short f2bf(float f) {
    unsigned int u = __float_as_uint(f);
    unsigned int r = u + 0x7FFFu + ((u >> 16) & 1u);
    return (unsigned short)(r >> 16);
}

// bare v_exp_f32: computes 2^x (inputs are pre-scaled by log2(e) at gather)
__device__ inline float exp2fast(float x) {
    float r;
    asm("v_exp_f32 %0, %1" : "=v"(r) : "v"(x));
    return r;
}

// global->LDS direct DMA, 16B/lane; LDS dest = wave-uniform base + lane*16.
__device__ inline void gl_lds16(const unsigned short* g, unsigned short* l) {
    __builtin_amdgcn_global_load_lds(
        reinterpret_cast<__attribute__((address_space(1))) unsigned int*>(
            reinterpret_cast<uintptr_t>(g)),
        reinterpret_cast<__attribute__((address_space(3))) unsigned int*>(
            reinterpret_cast<uintptr_t>(l)),
        16, 0, 0);
}

__device__ inline void wait_vmcnt0() { asm volatile("s_waitcnt vmcnt(0)" ::: "memory"); }
__device__ inline void raw_barrier() { asm volatile("s_barrier" ::: "memory"); }

// DPP 16-lane sum reduction — VALU only.
template<int CTRL>
__device__ inline float dpp_add(float x) {
    int v = __builtin_amdgcn_update_dpp(0, __float_as_int(x), CTRL, 0xF, 0xF, false);
    return x + __int_as_float(v);
}
__device__ inline float red16(float x) {
    x = dpp_add<0xB1>(x);    // quad_perm [1,0,3,2]
    x = dpp_add<0x4E>(x);    // quad_perm [2,3,0,1]
    x = dpp_add<0x141>(x);   // row_half_mirror
    x = dpp_add<0x140>(x);   // row_mirror
    return x;
}

// ---------------------------------------------------------------------------
// Kernel 1: gather + fp32->bf16 convert + fused en_score + denom zero-init.
// E rows are pre-scaled by log2(e) so kernel 2's exp is a bare v_exp_f32.
// z_bf is NOT scaled (kernel 3 consumes it as the B operand).
// (byte-identical to R4)
// ---------------------------------------------------------------------------
__global__ void gather_kernel(
    const float* __restrict__ zs,
    const float* __restrict__ W_en, const float* __restrict__ W_fr,
    const int* __restrict__ pos_en, const int* __restrict__ neg_en,
    const int* __restrict__ pos_fr, const int* __restrict__ neg_fr,
    const int* __restrict__ x_en,
    unsigned short* __restrict__ z_bf,
    unsigned short* __restrict__ E_en, unsigned short* __restrict__ E_fr,
    float* __restrict__ en_score,
    float* __restrict__ denom_en, float* __restrict__ denom_fr,
    int Pe, int Pf, int Lpe, int Lpf)
{
    int row  = blockIdx.x * 4 + (threadIdx.x >> 6);
    int lane = threadIdx.x & 63;
    const float* src = nullptr;
    unsigned short* dst = nullptr;
    bool zero = false;
    float sc = LOG2E;                 // E rows get the log2e pre-scale

    if (row < NTOK) {
        src = zs + (size_t)row * DDIM;
        dst = z_bf + (size_t)row * DDIM;
        sc = 1.0f;                    // z_bf stays unscaled
        if (lane == 0) { denom_en[row] = 0.0f; denom_fr[row] = 0.0f; }
    } else if (row < NTOK + Lpe) {
        int j = row - NTOK;
        int Le = Pe + NEGN;
        int idx = 0;
        if (j < Pe)      idx = pos_en[j];
        else if (j < Le) idx = neg_en[j - Pe];
        else             zero = true;
        src = W_en + (size_t)idx * DDIM;
        dst = E_en + (size_t)j * DDIM;
    } else if (row < NTOK + Lpe + Lpf) {
        int j = row - NTOK - Lpe;
        int Lf = Pf + NEGN;
        int idx = 0;
        if (j < Pf)      idx = pos_fr[j];
        else if (j < Lf) idx = neg_fr[j - Pf];
        else             zero = true;
        src = W_fr + (size_t)idx * DDIM;
        dst = E_fr + (size_t)j * DDIM;
    } else if (row < NTOK + Lpe + Lpf + NTOK) {
        // fused en_score: zs[j] . W_en[x_en[j]] in fp32, wave reduce
        int j = row - NTOK - Lpe - Lpf;
        int idx = x_en[j];
        float4 z = *(const float4*)(zs   + (size_t)j   * DDIM + lane * 4);
        float4 w = *(const float4*)(W_en + (size_t)idx * DDIM + lane * 4);
        float s = z.x * w.x + z.y * w.y + z.z * w.z + z.w * w.w;
        #pragma unroll
        for (int m = 32; m; m >>= 1) s += __shfl_xor(s, m);
        if (lane == 0) en_score[j] = s;
        return;
    } else {
        return;
    }

    int d = lane * 4;
    float4 v;
    if (zero) { v.x = v.y = v.z = v.w = 0.0f; }
    else      { v = *(const float4*)(src + d); }
    ushort4 o;
    o.x = f2bf(v.x * sc); o.y = f2bf(v.y * sc);
    o.z = f2bf(v.z * sc); o.w = f2bf(v.w * sc);
    *(ushort4*)(dst + d) = o;
}

// ---------------------------------------------------------------------------
// Kernel 2: fused denominators — R4 structure verbatim (best: 56.0us).
// R5/R6/R7 falsified the occupancy/domain/setprio family; R4 is the anchor.
// 512 blocks x 4 waves x 64m; 64n x 256k tile double-buffered (64KB);
// per-tile sync: own vmcnt(0) -> raw s_barrier -> STAGE(s+1); j-sweep
// ping-pong drain (acc matures per n-frag, drains under next sweep's MFMAs).
// Frag layouts (HW-verified): A/B lane holds row (lane&15), 8 k-halfs at
// (lane>>4)*8;  C/D: n-col = lane&15, m-row = (lane>>4)*4 + reg.
// ---------------------------------------------------------------------------
__global__ __launch_bounds__(256, 2) void expsum_stream(
    const unsigned short* __restrict__ A,   // z_bf [4096 x 256]
    const unsigned short* __restrict__ E,   // [Ltot x 256], pre-scaled log2e
    const float* __restrict__ kep, const float* __restrict__ kfp,
    float* __restrict__ out_en, float* __restrict__ out_fr,
    int Pe, int Pf, int Lpe, int NT)        // NT = Ltot/64 n-tiles
{
    // 2 tiles x 8 chunks x 4KB; chunk slab: 4 sub-blocks of 16 rows, each
    // packed lane-linear (lane*16B) for conflict-free DMA write + b128 read.
    __shared__ __align__(16) unsigned short Bs[2][8][2048];

    // 512 blocks: xcd = lin&7, m-tile xb = (lin>>3)&15, slice = xcd + 8*(lin>>7)
    // XCD k streams only tiles ≡ k (mod 8) -> 1/8 of E resident in its L2.
    int lin = blockIdx.y * 64 + blockIdx.x;
    int xcd = lin & 7;
    int xb  = (lin >> 3) & 15;
    int sl  = xcd + 8 * (lin >> 7);    // 0..31; tiles {sl, sl+32, ...}

    int t    = threadIdx.x;
    int lane = t & 63;
    int wave = t >> 6;
    int col  = lane & 15;
    int quad = lane >> 4;

    // kappas: load + pin BEFORE any DMA so the vmcnt queue stays clean
    float ke = kep[0], kf = kfp[0];
    asm volatile("" : "+v"(ke), "+v"(kf) : : "memory");

    // ---- A fragments in registers (one-time load; wave owns 64 m rows)
    bf16x8 afr[4][8];
    {
        const unsigned short* Ap =
            A + ((size_t)(xb * 256 + wave * 64 + col)) * DDIM + quad * 8;
        #pragma unroll
        for (int i = 0; i < 4; i++)
            #pragma unroll
            for (int c = 0; c < 8; c++)
                afr[i][c] = *(const bf16x8*)(Ap + (size_t)i * 16 * DDIM + c * 32);
    }

    float sums[4][4];
    #pragma unroll
    for (int i = 0; i < 4; i++)
        #pragma unroll
        for (int rr = 0; rr < 4; rr++) sums[i][rr] = 0.0f;

    f32x4 accA[4], accB[4];
    #pragma unroll
    for (int i = 0; i < 4; i++) accB[i] = (f32x4){0.f, 0.f, 0.f, 0.f};
    float wjP = 0.0f;                  // weight of the pending (accB) n-frag
    float* curout = out_en;
    int outrow = xb * 256 + wave * 64;

    int ntiles = (NT - sl + 31) >> 5;

    // stage tile s: this wave's 16-row sub-block for ALL 8 k-chunks (8 DMAs).
    #define STAGE_TILE(s) do {                                               \
        int tl_ = sl + ((s) << 5);                                           \
        const unsigned short* g_ =                                           \
            E + (size_t)(tl_ * 64 + wave * 16 + col) * DDIM + quad * 8;      \
        unsigned short* l_ = &Bs[(s) & 1][0][wave * 512];                    \
        _Pragma("unroll")                                                    \
        for (int kc_ = 0; kc_ < 8; kc_++)                                    \
            gl_lds16(g_ + kc_ * 32, l_ + kc_ * 2048);                        \
    } while (0)

    // full-K sweep for n-frag J: compute ACCC; drain ACCD (weight WJD) under
    // the MFMAs, 2 entries per chunk (16 entries over 8 chunks).
    #define J_SWEEP(J, ACCC, ACCD, WJD) do {                                 \
        _Pragma("unroll")                                                    \
        for (int i = 0; i < 4; i++) ACCC[i] = (f32x4){0.f, 0.f, 0.f, 0.f};   \
        _Pragma("unroll")                                                    \
        for (int k8 = 0; k8 < 8; k8++) {                                     \
            bf16x8 bfv = *(const bf16x8*)(                                   \
                &Bs[s & 1][k8][(J) * 512 + quad * 128 + col * 8]);           \
            _Pragma("unroll")                                                \
            for (int i = 0; i < 4; i++)                                      \
                ACCC[i] = __builtin_amdgcn_mfma_f32_16x16x32_bf16(           \
                    afr[i][k8], bfv, ACCC[i], 0, 0, 0);                      \
            sums[(k8 * 2) >> 2][(k8 * 2) & 3] +=                             \
                (WJD) * exp2fast(ACCD[(k8 * 2) >> 2][(k8 * 2) & 3]);         \
            sums[(k8 * 2 + 1) >> 2][(k8 * 2 + 1) & 3] +=                     \
                (WJD) * exp2fast(ACCD[(k8 * 2 + 1) >> 2][(k8 * 2 + 1) & 3]); \
        }                                                                    \
    } while (0)

    #define FLUSH_SUMS() do {                                                \
        _Pragma("unroll")                                                    \
        for (int i = 0; i < 4; i++)                                          \
            _Pragma("unroll")                                                \
            for (int rr = 0; rr < 4; rr++) {                                 \
                float v = red16(sums[i][rr]);                                \
                if (col == 0)                                                \
                    atomicAdd(curout + outrow + 16 * i + quad * 4 + rr, v);  \
                sums[i][rr] = 0.0f;                                          \
            }                                                                \
    } while (0)

    STAGE_TILE(0);

    for (int s = 0; s < ntiles; s++) {
        int tl = sl + (s << 5);
        int nb = tl * 64;

        wait_vmcnt0();      // my tile-s DMAs retired (issued 1 tile-period ago)
        raw_barrier();      // all waves' tile-s resident; all done reading s-1

        if (s + 1 < ntiles) STAGE_TILE(s + 1);   // 8 DMAs, fly under compute

        // arithmetic weights: n < P -> 1 ; n < P+NEGN -> kappa ; else 0 (pad)
        float wj[4];
        #pragma unroll
        for (int j = 0; j < 4; j++) {
            int ngl = nb + 16 * j + col;
            if (nb < Lpe) {
                wj[j] = (ngl < Pe) ? 1.0f : ((ngl < Pe + NEGN) ? ke : 0.0f);
            } else {
                int nl = ngl - Lpe;
                wj[j] = (nl < Pf) ? 1.0f : ((nl < Pf + NEGN) ? kf : 0.0f);
            }
        }
        float* outC = (nb >= Lpe) ? out_fr : out_en;

        // j0: drains the pending frag (prev tile's j3, weight wjP, out curout)
        J_SWEEP(0, accA, accB, wjP);
        if (outC != curout) {          // en->fr boundary: taken once per block
            FLUSH_SUMS();
            curout = outC;
        }
        J_SWEEP(1, accB, accA, wj[0]);
        J_SWEEP(2, accA, accB, wj[1]);
        J_SWEEP(3, accB, accA, wj[2]);
        wjP = wj[3];                   // accB (j3) pends into the next tile
    }
    #undef STAGE_TILE
    #undef J_SWEEP

    // drain the final pending frag, then flush
    #pragma unroll
    for (int i = 0; i < 4; i++)
        #pragma unroll
        for (int rr = 0; rr < 4; rr++)
            sums[i][rr] += wjP * exp2fast(accB[i][rr]);
    FLUSH_SUMS();
    #undef FLUSH_SUMS
}

// ---------------------------------------------------------------------------
// Kernel 3: fr alignment — SINGLE-BURST rewrite. Old structure: 8 k-iters
// each with 2 __syncthreads and loads issued at iteration top -> ~8 exposed
// latency+rendezvous periods. New: issue ALL global loads up front (16x
// float4 A + 8x uint4 B per thread, ~96 transient VGPRs), convert, write the
// whole 8-chunk A/B tile to LDS (8x[64][LDT] each, 80 KB total - fine at 64
// blocks / <=1 block/CU), ONE __syncthreads, then 8 chunks of pure
// ds_read+MFMA with zero barriers. Epilogue identical to R4 (exp2fast,
// 1/denom_fr weights, fused en/fr loss).
// ---------------------------------------------------------------------------
__global__ __launch_bounds__(256) void expsum_gemm64_loss(
    const float* __restrict__ W_fr,         // [V_FR x 256] fp32
    const int* __restrict__ x_fr,           // [B*64]
    const unsigned short* __restrict__ Bm,  // z_bf  [B][64 x 256]
    const float* __restrict__ denom_fr,     // [B*64]
    const float* __restrict__ denom_en,     // [B*64]
    const float* __restrict__ en_score,     // [B*64]
    const float* __restrict__ en_mask,
    const float* __restrict__ fr_mask,
    float* __restrict__ outloss)            // [128]: en | fr
{
    __shared__ __align__(16) unsigned short lda[8][TM * LDT];  // 40 KB
    __shared__ __align__(16) unsigned short ldb[8][TN * LDT];  // 40 KB
    __shared__ float tbuf[64];

    int batch = blockIdx.x;
    const unsigned short* Bb = Bm + (size_t)batch * TN * DDIM;

    int t      = threadIdx.x;
    int srow   = t >> 2;
    int schunk = t & 3;
    int lane   = t & 63;
    int wave   = t >> 6;
    int col    = lane & 15;
    int quad   = lane >> 4;

    int aidx = x_fr[batch * 64 + srow];
    const float* Arow = W_fr + (size_t)aidx * DDIM;

    // ---- burst: issue every global load, one latency exposure
    float4 fa[16];
    uint4  fb[8];
    #pragma unroll
    for (int kk = 0; kk < 8; kk++) {
        fa[2 * kk]     = *(const float4*)(Arow + kk * 32 + schunk * 8);
        fa[2 * kk + 1] = *(const float4*)(Arow + kk * 32 + schunk * 8 + 4);
        fb[kk] = *(const uint4*)(Bb + (size_t)srow * DDIM + kk * 32 + schunk * 8);
    }

    // ---- convert + write the whole tile to LDS
    #pragma unroll
    for (int kk = 0; kk < 8; kk++) {
        ushort4 ua, ub;
        ua.x = f2bf(fa[2 * kk].x * LOG2E);     ua.y = f2bf(fa[2 * kk].y * LOG2E);
        ua.z = f2bf(fa[2 * kk].z * LOG2E);     ua.w = f2bf(fa[2 * kk].w * LOG2E);
        ub.x = f2bf(fa[2 * kk + 1].x * LOG2E); ub.y = f2bf(fa[2 * kk + 1].y * LOG2E);
        ub.z = f2bf(fa[2 * kk + 1].z * LOG2E); ub.w = f2bf(fa[2 * kk + 1].w * LOG2E);
        *(ushort4*)(&lda[kk][srow * LDT + schunk * 8])     = ua;
        *(ushort4*)(&lda[kk][srow * LDT + schunk * 8 + 4]) = ub;
        *(uint4*)(&ldb[kk][srow * LDT + schunk * 8]) = fb[kk];
    }
    __syncthreads();                       // the only barrier before compute

    f32x4 acc0 = {0.f,0.f,0.f,0.f};
    f32x4 acc1 = {0.f,0.f,0.f,0.f};
    f32x4 acc2 = {0.f,0.f,0.f,0.f};
    f32x4 acc3 = {0.f,0.f,0.f,0.f};

    #pragma unroll
    for (int kk = 0; kk < 8; kk++) {
        bf16x8 af = *(const bf16x8*)(&lda[kk][(wave * 16 + col) * LDT + quad * 8]);
        bf16x8 b0 = *(const bf16x8*)(&ldb[kk][( 0 + col) * LDT + quad * 8]);
        bf16x8 b1 = *(const bf16x8*)(&ldb[kk][(16 + col) * LDT + quad * 8]);
        bf16x8 b2 = *(const bf16x8*)(&ldb[kk][(32 + col) * LDT + quad * 8]);
        bf16x8 b3 = *(const bf16x8*)(&ldb[kk][(48 + col) * LDT + quad * 8]);
        acc0 = __builtin_amdgcn_mfma_f32_16x16x32_bf16(af, b0, acc0, 0, 0, 0);
        acc1 = __builtin_amdgcn_mfma_f32_16x16x32_bf16(af, b1, acc1, 0, 0, 0);
        acc2 = __builtin_amdgcn_mfma_f32_16x16x32_bf16(af, b2, acc2, 0, 0, 0);
        acc3 = __builtin_amdgcn_mfma_f32_16x16x32_bf16(af, b3, acc3, 0, 0, 0);
    }

    const float* db = denom_fr + batch * 64;
    float w0 = 1.0f / db[ 0 + col];
    float w1 = 1.0f / db[16 + col];
    float w2 = 1.0f / db[32 + col];
    float w3 = 1.0f / db[48 + col];

    float tot0 = w0 * exp2fast(acc0.x) + w1 * exp2fast(acc1.x) + w2 * exp2fast(acc2.x) + w3 * exp2fast(acc3.x);
    float tot1 = w0 * exp2fast(acc0.y) + w1 * exp2fast(acc1.y) + w2 * exp2fast(acc2.y) + w3 * exp2fast(acc3.y);
    float tot2 = w0 * exp2fast(acc0.z) + w1 * exp2fast(acc1.z) + w2 * exp2fast(acc2.z) + w3 * exp2fast(acc3.z);
    float tot3 = w0 * exp2fast(acc0.w) + w1 * exp2fast(acc1.w) + w2 * exp2fast(acc2.w) + w3 * exp2fast(acc3.w);

    #pragma unroll
    for (int m = 1; m < 16; m <<= 1) {
        tot0 += __shfl_xor(tot0, m);
        tot1 += __shfl_xor(tot1, m);
        tot2 += __shfl_xor(tot2, m);
        tot3 += __shfl_xor(tot3, m);
    }
    if (col == 0) {
        int base = wave * 16 + quad * 4;
        tbuf[base + 0] = tot0; tbuf[base + 1] = tot1;
        tbuf[base + 2] = tot2; tbuf[base + 3] = tot3;
    }
    __syncthreads();

    if (t < 64) {
        int i = batch * 64 + t;
        float a = (en_score[i] - __logf(denom_en[i])) * en_mask[i];
        float c = __logf(tbuf[t]) * fr_mask[i];
        #pragma unroll
        for (int m = 32; m; m >>= 1) { a += __shfl_xor(a, m); c += __shfl_xor(c, m); }
        if (t == 0) { outloss[batch] = a; outloss[64 + batch] = c; }
    }
}

extern "C" void kernel_launch(void* const* d_in, const int* in_sizes, int n_in,
                              void* d_out, int out_size, void* d_ws, size_t ws_size,
                              hipStream_t stream)
{
    const float* zs       = (const float*)d_in[0];
    const int*   x_en     = (const int*)d_in[1];
    const int*   x_fr     = (const int*)d_in[2];
    const float* en_mask  = (const float*)d_in[3];
    const float* fr_mask  = (const float*)d_in[4];
    const float* W_en     = (const float*)d_in[5];
    const float* W_fr     = (const float*)d_in[6];
    const int*   pos_en   = (const int*)d_in[7];
    const int*   neg_en   = (const int*)d_in[8];
    const int*   pos_fr   = (const int*)d_in[9];
    const int*   neg_fr   = (const int*)d_in[10];
    const float* kappa_en = (const float*)d_in[11];
    const float* kappa_fr = (const float*)d_in[12];

    int Pe  = in_sizes[7];
    int Pf  = in_sizes[9];
    int Lpe = (Pe + NEGN + 63) & ~63;     // 64-aligned n-tiles (no straddle)
    int Lpf = (Pf + NEGN + 63) & ~63;
    int Ltot = Lpe + Lpf;
    int NT   = Ltot / 64;

    char* w = (char*)d_ws;
    float* denom_en = (float*)w; w += NTOK * 4;
    float* denom_fr = (float*)w; w += NTOK * 4;
    float* en_score = (float*)w; w += NTOK * 4;
    unsigned short* z_bf  = (unsigned short*)w; w += (size_t)NTOK * DDIM * 2;
    unsigned short* E_all = (unsigned short*)w; w += (size_t)Ltot * DDIM * 2;

    int totrows = NTOK + Lpe + Lpf + NTOK;
    gather_kernel<<<(totrows + 3) / 4, 256, 0, stream>>>(
        zs, W_en, W_fr, pos_en, neg_en, pos_fr, neg_fr, x_en,
        z_bf, E_all, E_all + (size_t)Lpe * DDIM,
        en_score, denom_en, denom_fr, Pe, Pf, Lpe, Lpf);

    // fused denominators: R4 structure verbatim (best measured: 56.0 us)
    expsum_stream<<<dim3(64, 8), 256, 0, stream>>>(
        z_bf, E_all, kappa_en, kappa_fr, denom_en, denom_fr, Pe, Pf, Lpe, NT);

    // fr alignment: single-burst, single-barrier rewrite
    expsum_gemm64_loss<<<64, 256, 0, stream>>>(
        W_fr, x_fr, z_bf, denom_fr, denom_en, en_score, en_mask, fr_mask,
        (float*)d_out);
}